// Round 3
// baseline (146.997 us; speedup 1.0000x reference)
//
#include <hip/hip_runtime.h>
#include <math.h>

#define BATCH 8
#define CH    64
#define HH    128
#define WW    128
#define HWSZ  (HH * WW)       // 16384
#define COUT  64
#define KTAPS 9
#define KDIM  576             // CH * KTAPS
#define TROWS 6               // window rows: y-2 .. y+3
#define TCOLS 36              // window cols: x0-2 .. x0+33
#define TSLOTS 216            // 6 * 36
#define WSEGU 1736            // ushorts per ch-segment (216*8=1728, +8 pad:
                              // 868 dw ≡ 4 mod 32 -> 8 segs on 8 bank phases)

typedef __attribute__((ext_vector_type(8))) short short8;
typedef __attribute__((ext_vector_type(4))) float f32x4;
typedef __attribute__((ext_vector_type(2))) float f32x2;

__device__ __forceinline__ unsigned short f2bf(float f) {
    unsigned int u = __float_as_uint(f);
    u += 0x7fffu + ((u >> 16) & 1u);
    return (unsigned short)(u >> 16);
}
__device__ __forceinline__ f32x2 up2(unsigned int u) {
    f32x2 r;
    r.x = __uint_as_float(u << 16);
    r.y = __uint_as_float(u & 0xffff0000u);
    return r;
}
__device__ __forceinline__ unsigned int bilin2(unsigned int a, unsigned int b,
                                               unsigned int c, unsigned int d,
                                               float w00, float w01, float w10, float w11) {
    f32x2 acc = up2(a) * w00;
    acc = up2(b) * w01 + acc;
    acc = up2(c) * w10 + acc;
    acc = up2(d) * w11 + acc;
    return __builtin_amdgcn_perm(__float_as_uint(acc.y) + 0x8000u,
                                 __float_as_uint(acc.x) + 0x8000u, 0x07060302u);
}

// ---------------------------------------------------------------------------
// Kernel 0: repack conv weights into wave-contiguous A-fragment layouts.
//  wpk [mt<4][ks<18][lane<64][8]: lane(n16,quad) holds
//      w_dcn[co=mt*16+n16][c=(ks&1)*32+quad*8+j], tap=ks>>1
//  wopk[cot<2][ks<18][lane<64][8]: same for w_off (co>=27 zeroed)
// ---------------------------------------------------------------------------
__global__ __launch_bounds__(256) void prep_w_kernel(
    const float* __restrict__ w_dcn, const float* __restrict__ w_off,
    unsigned short* __restrict__ wpk, unsigned short* __restrict__ wopk) {
    int j = blockIdx.x * 256 + threadIdx.x;
    if (j < 36864) {
        int jj = j & 7, ln = (j >> 3) & 63, q = j >> 9;   // q: 0..71
        int ks = q % 18, mt = q / 18;
        int tap = ks >> 1, h = ks & 1;
        int co = mt * 16 + (ln & 15);
        int c  = h * 32 + (ln >> 4) * 8 + jj;
        wpk[j] = f2bf(w_dcn[(co * CH + c) * KTAPS + tap]);
    } else if (j < 55296) {
        int jo = j - 36864;
        int jj = jo & 7, ln = (jo >> 3) & 63, q = jo >> 9; // q: 0..35
        int ks = q % 18, cot = q / 18;
        int tap = ks >> 1, h = ks & 1;
        int co = cot * 16 + (ln & 15);
        int c  = h * 32 + (ln >> 4) * 8 + jj;
        wopk[jo] = (co < 27) ? f2bf(w_off[(co * CH + c) * KTAPS + tap]) : 0;
    }
}

// ---------------------------------------------------------------------------
// Kernel 1: SINGLE FUSED DCN. Block tile = 2 rows x 32 cols (64 px).
//  Stage: win[c8][216 slots][8ch] bf16 <- 6x36 neighborhood straight from
//         NCHW fp32 x (zero-padded OOB). Bank-clean (WSEGU pad).
//  Phase 1: offset GEMM 32co x 64px, B-frags ds_read_b128 from window.
//  Phase 2: PER-LANE, REGISTER-ONLY bilinear params. Each thread computes
//           wgt/idx for ITS phase-3 px (pl = wv*16+n16), all 9 taps, into
//           registers (quad-redundant x4). No LDS wgt/idx, no extra barriers,
//           no aliasing.
//  Phase 3: barrier-free, fully unrolled; B-fragments built in registers
//           straight from the window (lane (quad,n16) holds channels
//           h*32+quad*8+j of px n16).
// LDS: win 27776 | omr 6912 = 34688 B -> 4 blocks/CU (16 waves).
// ---------------------------------------------------------------------------
__global__ __launch_bounds__(256, 4) void dcn_fused_mfma(
    const float* __restrict__ x, const unsigned short* __restrict__ wpk,
    const unsigned short* __restrict__ wopk, const float* __restrict__ b_off,
    const float* __restrict__ b_dcn, float* __restrict__ out) {
    __shared__ __align__(16) unsigned char smem[34688];
    unsigned short* win = (unsigned short*)smem;           // [8][WSEGU]
    float* omr = (float*)(smem + 27776);                   // [27][64]

    int tid = threadIdx.x, bid = blockIdx.x;
    int b = bid & 7;                 // batch -> XCD pinning
    int T = bid >> 3;                // tile 0..255 per image
    int y = (T >> 2) * 2;            // tile row base (2 rows)
    int x0 = (T & 3) * 32;           // tile col base
    int lane = tid & 63, wv = tid >> 6;
    int quad = lane >> 4, n16 = lane & 15;

    const float* xbf = x + (size_t)b * CH * HWSZ;

    // ---------------- Stage window from NCHW fp32 ----------------
    for (int p = tid; p < 8 * TSLOTS; p += 256) {
        int c8 = p / TSLOTS, slot = p - c8 * TSLOTS;
        int wy = slot / TCOLS, wx = slot - wy * TCOLS;
        int iy = y - 2 + wy, ix = x0 - 2 + wx;
        bool v = (iy >= 0) & (iy < HH) & (ix >= 0) & (ix < WW);
        uint4 q = {0, 0, 0, 0};
        if (v) {
            const float* pc0 = xbf + (size_t)(c8 * 8) * HWSZ + iy * WW + ix;
            unsigned int u0 = f2bf(pc0[0]);
            unsigned int u1 = f2bf(pc0[HWSZ]);
            unsigned int u2 = f2bf(pc0[2 * HWSZ]);
            unsigned int u3 = f2bf(pc0[3 * HWSZ]);
            unsigned int u4 = f2bf(pc0[4 * HWSZ]);
            unsigned int u5 = f2bf(pc0[5 * HWSZ]);
            unsigned int u6 = f2bf(pc0[6 * HWSZ]);
            unsigned int u7 = f2bf(pc0[7 * HWSZ]);
            q.x = u0 | (u1 << 16);
            q.y = u2 | (u3 << 16);
            q.z = u4 | (u5 << 16);
            q.w = u6 | (u7 << 16);
        }
        *(uint4*)&win[c8 * WSEGU + slot * 8] = q;
    }
    __syncthreads();

    // ---------------- Phase 1: offset GEMM (B from window) ----------------
    {
        int coh = wv & 1;
        int pxh = (wv >> 1) * 32;
        int prw = wv >> 1;               // this wave's px row within tile
        f32x4 oacc[2] = {{0, 0, 0, 0}, {0, 0, 0, 0}};
        for (int k = 0; k < KTAPS; ++k) {
            int ky = k / 3, kx = k - ky * 3;
#pragma unroll
            for (int h = 0; h < 2; ++h) {
                short8 afrag = *(const short8*)(wopk + (size_t)((coh * 18 + k * 2 + h) * 64 + lane) * 8);
                const unsigned short* seg = win + (h * 4 + quad) * WSEGU;
#pragma unroll
                for (int pt = 0; pt < 2; ++pt) {
                    int pc = pt * 16 + n16;
                    int slot = (prw + ky + 1) * TCOLS + pc + kx + 1;
                    short8 bfrag = *(const short8*)(seg + slot * 8);
                    oacc[pt] = __builtin_amdgcn_mfma_f32_16x16x32_bf16(afrag, bfrag,
                                                                       oacc[pt], 0, 0, 0);
                }
            }
        }
#pragma unroll
        for (int pt = 0; pt < 2; ++pt) {
#pragma unroll
            for (int r = 0; r < 4; ++r) {
                int co = coh * 16 + quad * 4 + r;
                if (co < 27) omr[co * 64 + pxh + pt * 16 + n16] = oacc[pt][r] + b_off[co];
            }
        }
    }
    __syncthreads();

    // ---------------- Phase 2: per-lane bilinear params -> REGISTERS ------
    // Thread computes wgt/idx for its own phase-3 px (pl), all 9 taps.
    // 4 threads (quads) per px do this redundantly; omr reads are
    // 16-words/wave -> conflict-free broadcast groups.
    int pl = wv * 16 + n16;
    int pr = pl >> 5, pcc = pl & 31;
    int ho = y + pr, wo = x0 + pcc;
    float4 wgtr[9];
    unsigned int idxr[9];
#pragma unroll
    for (int tap = 0; tap < KTAPS; ++tap) {
        float fy = omr[tap * 64 + pl] + (float)(ho - 1 + tap / 3);
        float fx = omr[(9 + tap) * 64 + pl] + (float)(wo - 1 + tap % 3);
        float m = 1.f / (1.f + __expf(-omr[(18 + tap) * 64 + pl]));
        float y0f = floorf(fy), x0f = floorf(fx);
        float dy = fy - y0f, dx = fx - x0f;
        int y0 = (int)y0f, x0i = (int)x0f;
        int y1 = y0 + 1, x1 = x0i + 1;
        bool vy0 = (y0 >= 0) & (y0 < HH);
        bool vy1 = (y1 >= 0) & (y1 < HH);
        bool vx0 = (x0i >= 0) & (x0i < WW);
        bool vx1 = (x1 >= 0) & (x1 < WW);
        float w00 = (1.f - dy) * (1.f - dx) * m; if (!(vy0 && vx0)) w00 = 0.f;
        float w01 = (1.f - dy) * dx * m;         if (!(vy0 && vx1)) w01 = 0.f;
        float w10 = dy * (1.f - dx) * m;         if (!(vy1 && vx0)) w10 = 0.f;
        float w11 = dy * dx * m;                 if (!(vy1 && vx1)) w11 = 0.f;
        int yc0 = min(max(y0, 0), HH - 1), yc1 = min(max(y1, 0), HH - 1);
        int xc0 = min(max(x0i, 0), WW - 1), xc1 = min(max(x1, 0), WW - 1);
        wgtr[tap] = make_float4(w00, w01, w10, w11);

        // window slot (unclamped base); corners s, s+1, s+36, s+37
        int uy = y0 - (y - 2), ux = x0i - (x0 - 2);
        bool inw = ((unsigned)uy <= 4u) & ((unsigned)ux <= 34u);
        unsigned int enc;
        if (inw) enc = (unsigned)(uy * TCOLS + ux);
        else     enc = 0x80000000u | ((unsigned)yc0 << 21) | ((unsigned)xc0 << 14)
                                   | ((unsigned)yc1 << 7)  | (unsigned)xc1;
        idxr[tap] = enc;
    }
    // No barrier: phase 2 writes nothing shared; phase 3 reads only win.

    // ---------------- Phase 3: main GEMM, barrier-free, B in registers ----
    // Wave wv owns px = wv*16 + n16 (all 64 co). Lane (quad,n16) builds the
    // exact MFMA B-fragment: channels h*32+quad*8+j of its px, h = 0,1.
    f32x4 acc[4] = {{0, 0, 0, 0}, {0, 0, 0, 0}, {0, 0, 0, 0}, {0, 0, 0, 0}};

#pragma unroll
    for (int k = 0; k < KTAPS; ++k) {
        float4 w4 = wgtr[k];
        unsigned int iu = idxr[k];

        // A-fragments for all 4 co-tiles, both k-halves (L1/L2-shared)
        short8 af0[4], af1[4];
#pragma unroll
        for (int mt = 0; mt < 4; ++mt) {
            af0[mt] = *(const short8*)(wpk + (size_t)((mt * 18 + k * 2 + 0) * 64 + lane) * 8);
            af1[mt] = *(const short8*)(wpk + (size_t)((mt * 18 + k * 2 + 1) * 64 + lane) * 8);
        }

#pragma unroll
        for (int h = 0; h < 2; ++h) {
            int g = h * 4 + quad;                 // channel-group / win segment
            uint4 qa, qb, qc, qd;
            if (__builtin_expect(!(iu & 0x80000000u), 1)) {
                const unsigned short* base = win + g * WSEGU + iu * 8;
                qa = *(const uint4*)(base);
                qb = *(const uint4*)(base + 8);
                qc = *(const uint4*)(base + TCOLS * 8);
                qd = *(const uint4*)(base + TCOLS * 8 + 8);
            } else {
                int yc0 = (iu >> 21) & 0x7f, xc0 = (iu >> 14) & 0x7f;
                int yc1 = (iu >> 7) & 0x7f,  xc1 = iu & 0x7f;
                const float* pc0 = xbf + (size_t)(g * 8) * HWSZ;
                auto ld8 = [&](int yy, int xx) {
                    const float* p = pc0 + yy * WW + xx;
                    unsigned int u0 = f2bf(p[0]),        u1 = f2bf(p[HWSZ]);
                    unsigned int u2 = f2bf(p[2 * HWSZ]), u3 = f2bf(p[3 * HWSZ]);
                    unsigned int u4 = f2bf(p[4 * HWSZ]), u5 = f2bf(p[5 * HWSZ]);
                    unsigned int u6 = f2bf(p[6 * HWSZ]), u7 = f2bf(p[7 * HWSZ]);
                    uint4 q;
                    q.x = u0 | (u1 << 16); q.y = u2 | (u3 << 16);
                    q.z = u4 | (u5 << 16); q.w = u6 | (u7 << 16);
                    return q;
                };
                qa = ld8(yc0, xc0); qb = ld8(yc0, xc1);
                qc = ld8(yc1, xc0); qd = ld8(yc1, xc1);
            }
            union { uint4 u; short8 s; } cv;
            cv.u.x = bilin2(qa.x, qb.x, qc.x, qd.x, w4.x, w4.y, w4.z, w4.w);
            cv.u.y = bilin2(qa.y, qb.y, qc.y, qd.y, w4.x, w4.y, w4.z, w4.w);
            cv.u.z = bilin2(qa.z, qb.z, qc.z, qd.z, w4.x, w4.y, w4.z, w4.w);
            cv.u.w = bilin2(qa.w, qb.w, qc.w, qd.w, w4.x, w4.y, w4.z, w4.w);
            short8 bfrag = cv.s;
#pragma unroll
            for (int mt = 0; mt < 4; ++mt) {
                short8 afrag = h ? af1[mt] : af0[mt];
                acc[mt] = __builtin_amdgcn_mfma_f32_16x16x32_bf16(afrag, bfrag,
                                                                  acc[mt], 0, 0, 0);
            }
        }
    }

    // Epilogue: D[m=quad*4+r][n=n16]; co = mt*16 + m; px = wv*16 + n16
    float* ob = out + (size_t)b * COUT * HWSZ;
    int gidx = (y + (pl >> 5)) * WW + x0 + (pl & 31);
#pragma unroll
    for (int mt = 0; mt < 4; ++mt) {
#pragma unroll
        for (int r = 0; r < 4; ++r) {
            int co = mt * 16 + quad * 4 + r;
            ob[(size_t)co * HWSZ + gidx] = acc[mt][r] + b_dcn[co];
        }
    }
}

// ---------------------------------------------------------------------------
extern "C" void kernel_launch(void* const* d_in, const int* in_sizes, int n_in,
                              void* d_out, int out_size, void* d_ws, size_t ws_size,
                              hipStream_t stream) {
    const float* x     = (const float*)d_in[0];
    const float* w_off = (const float*)d_in[1];
    const float* b_off = (const float*)d_in[2];
    const float* w_dcn = (const float*)d_in[3];
    const float* b_dcn = (const float*)d_in[4];
    float* out = (float*)d_out;

    // ws layout: wpk | wopk (bf16 repacked weights only)
    unsigned short* wpk  = (unsigned short*)d_ws;            // 36864
    unsigned short* wopk = wpk + 36864;                      // 18432

    hipLaunchKernelGGL(prep_w_kernel, dim3(216), dim3(256), 0, stream,
                       w_dcn, w_off, wpk, wopk);
    hipLaunchKernelGGL(dcn_fused_mfma, dim3(BATCH * HWSZ / 64), dim3(256),
                       0, stream, x, wpk, wopk, b_off, b_dcn, out);
}

// Round 4
// 130.357 us; speedup vs baseline: 1.1276x; 1.1276x over previous
//
#include <hip/hip_runtime.h>
#include <math.h>

#define BATCH 8
#define CH    64
#define HH    128
#define WW    128
#define HWSZ  (HH * WW)       // 16384
#define COUT  64
#define KTAPS 9
#define KDIM  576             // CH * KTAPS
#define TROWS 6               // window rows: y-2 .. y+3
#define TCOLS 36              // window cols: x0-2 .. x0+33
#define TSLOTS 216            // 6 * 36
#define WSEGU 1736            // ushorts per ch-segment (216*8=1728, +8 pad:
                              // 868 dw ≡ 4 mod 32 -> 8 segs on 8 bank phases)

typedef __attribute__((ext_vector_type(8))) short short8;
typedef __attribute__((ext_vector_type(4))) float f32x4;
typedef __attribute__((ext_vector_type(2))) float f32x2;

__device__ __forceinline__ unsigned short f2bf(float f) {
    unsigned int u = __float_as_uint(f);
    u += 0x7fffu + ((u >> 16) & 1u);
    return (unsigned short)(u >> 16);
}
__device__ __forceinline__ f32x2 up2(unsigned int u) {
    f32x2 r;
    r.x = __uint_as_float(u << 16);
    r.y = __uint_as_float(u & 0xffff0000u);
    return r;
}
__device__ __forceinline__ unsigned int bilin2(unsigned int a, unsigned int b,
                                               unsigned int c, unsigned int d,
                                               float w00, float w01, float w10, float w11) {
    f32x2 acc = up2(a) * w00;
    acc = up2(b) * w01 + acc;
    acc = up2(c) * w10 + acc;
    acc = up2(d) * w11 + acc;
    return __builtin_amdgcn_perm(__float_as_uint(acc.y) + 0x8000u,
                                 __float_as_uint(acc.x) + 0x8000u, 0x07060302u);
}

// ---------------------------------------------------------------------------
// Kernel 0: repack conv weights into wave-contiguous A-fragment layouts.
//  wpk [mt<4][ks<18][lane<64][8]: lane(n16,quad) holds
//      w_dcn[co=mt*16+n16][c=(ks&1)*32+quad*8+j], tap=ks>>1
//  wopk[cot<2][ks<18][lane<64][8]: same for w_off (co>=27 zeroed)
// ---------------------------------------------------------------------------
__global__ __launch_bounds__(256) void prep_w_kernel(
    const float* __restrict__ w_dcn, const float* __restrict__ w_off,
    unsigned short* __restrict__ wpk, unsigned short* __restrict__ wopk) {
    int j = blockIdx.x * 256 + threadIdx.x;
    if (j < 36864) {
        int jj = j & 7, ln = (j >> 3) & 63, q = j >> 9;   // q: 0..71
        int ks = q % 18, mt = q / 18;
        int tap = ks >> 1, h = ks & 1;
        int co = mt * 16 + (ln & 15);
        int c  = h * 32 + (ln >> 4) * 8 + jj;
        wpk[j] = f2bf(w_dcn[(co * CH + c) * KTAPS + tap]);
    } else if (j < 55296) {
        int jo = j - 36864;
        int jj = jo & 7, ln = (jo >> 3) & 63, q = jo >> 9; // q: 0..35
        int ks = q % 18, cot = q / 18;
        int tap = ks >> 1, h = ks & 1;
        int co = cot * 16 + (ln & 15);
        int c  = h * 32 + (ln >> 4) * 8 + jj;
        wopk[jo] = (co < 27) ? f2bf(w_off[(co * CH + c) * KTAPS + tap]) : 0;
    }
}

// ---------------------------------------------------------------------------
// Kernel 1: SINGLE FUSED DCN. Block tile = 2 rows x 32 cols (64 px).
//  Stage: win[c8][216 slots][8ch] bf16 <- 6x36 neighborhood straight from
//         NCHW fp32 x (zero-padded OOB). Bank-clean (WSEGU pad).
//  Phase 1: offset GEMM 32co x 64px, B-frags ds_read_b128 from window.
//  Phase 3 (phase 2 FUSED IN): per tap, each thread computes bilinear params
//           for ITS px (pl = wv*16+n16) from omr (3 broadcast ds_reads +
//           ~30 VALU) as PLAIN SCALARS — no param arrays exist, so nothing
//           can go to scratch (R3 lesson: VGPR=64 + 86MB HBM = spilled
//           wgtr/idxr). B-fragments built in registers from the window.
// LDS: win 27776 | omr 6912 = 34688 B -> 4 blocks/CU (16 waves).
// Reg budget: launch_bounds(256,4) caps at 128 VGPR; peak demand ~90.
// ---------------------------------------------------------------------------
__global__ __launch_bounds__(256, 4) void dcn_fused_mfma(
    const float* __restrict__ x, const unsigned short* __restrict__ wpk,
    const unsigned short* __restrict__ wopk, const float* __restrict__ b_off,
    const float* __restrict__ b_dcn, float* __restrict__ out) {
    __shared__ __align__(16) unsigned char smem[34688];
    unsigned short* win = (unsigned short*)smem;           // [8][WSEGU]
    float* omr = (float*)(smem + 27776);                   // [27][64]

    int tid = threadIdx.x, bid = blockIdx.x;
    int b = bid & 7;                 // batch -> XCD pinning
    int T = bid >> 3;                // tile 0..255 per image
    int y = (T >> 2) * 2;            // tile row base (2 rows)
    int x0 = (T & 3) * 32;           // tile col base
    int lane = tid & 63, wv = tid >> 6;
    int quad = lane >> 4, n16 = lane & 15;

    const float* xbf = x + (size_t)b * CH * HWSZ;

    // ---------------- Stage window from NCHW fp32 ----------------
    for (int p = tid; p < 8 * TSLOTS; p += 256) {
        int c8 = p / TSLOTS, slot = p - c8 * TSLOTS;
        int wy = slot / TCOLS, wx = slot - wy * TCOLS;
        int iy = y - 2 + wy, ix = x0 - 2 + wx;
        bool v = (iy >= 0) & (iy < HH) & (ix >= 0) & (ix < WW);
        uint4 q = {0, 0, 0, 0};
        if (v) {
            const float* pc0 = xbf + (size_t)(c8 * 8) * HWSZ + iy * WW + ix;
            unsigned int u0 = f2bf(pc0[0]);
            unsigned int u1 = f2bf(pc0[HWSZ]);
            unsigned int u2 = f2bf(pc0[2 * HWSZ]);
            unsigned int u3 = f2bf(pc0[3 * HWSZ]);
            unsigned int u4 = f2bf(pc0[4 * HWSZ]);
            unsigned int u5 = f2bf(pc0[5 * HWSZ]);
            unsigned int u6 = f2bf(pc0[6 * HWSZ]);
            unsigned int u7 = f2bf(pc0[7 * HWSZ]);
            q.x = u0 | (u1 << 16);
            q.y = u2 | (u3 << 16);
            q.z = u4 | (u5 << 16);
            q.w = u6 | (u7 << 16);
        }
        *(uint4*)&win[c8 * WSEGU + slot * 8] = q;
    }
    __syncthreads();

    // ---------------- Phase 1: offset GEMM (B from window) ----------------
    {
        int coh = wv & 1;
        int pxh = (wv >> 1) * 32;
        int prw = wv >> 1;               // this wave's px row within tile
        f32x4 oacc[2] = {{0, 0, 0, 0}, {0, 0, 0, 0}};
        for (int k = 0; k < KTAPS; ++k) {
            int ky = k / 3, kx = k - ky * 3;
#pragma unroll
            for (int h = 0; h < 2; ++h) {
                short8 afrag = *(const short8*)(wopk + (size_t)((coh * 18 + k * 2 + h) * 64 + lane) * 8);
                const unsigned short* seg = win + (h * 4 + quad) * WSEGU;
#pragma unroll
                for (int pt = 0; pt < 2; ++pt) {
                    int pc = pt * 16 + n16;
                    int slot = (prw + ky + 1) * TCOLS + pc + kx + 1;
                    short8 bfrag = *(const short8*)(seg + slot * 8);
                    oacc[pt] = __builtin_amdgcn_mfma_f32_16x16x32_bf16(afrag, bfrag,
                                                                       oacc[pt], 0, 0, 0);
                }
            }
        }
#pragma unroll
        for (int pt = 0; pt < 2; ++pt) {
#pragma unroll
            for (int r = 0; r < 4; ++r) {
                int co = coh * 16 + quad * 4 + r;
                if (co < 27) omr[co * 64 + pxh + pt * 16 + n16] = oacc[pt][r] + b_off[co];
            }
        }
    }
    __syncthreads();

    // ---------------- Phase 3: main GEMM, params fused per tap ------------
    // Wave wv owns px = wv*16 + n16 (all 64 co). Lane (quad,n16) builds the
    // exact MFMA B-fragment: channels h*32+quad*8+j of its px, h = 0,1.
    // Per tap: 3 omr reads (quad-broadcast) -> w4/iu scalars -> window/global
    // corners -> bilin -> 8 MFMA. No persistent arrays beyond acc.
    f32x4 acc[4] = {{0, 0, 0, 0}, {0, 0, 0, 0}, {0, 0, 0, 0}, {0, 0, 0, 0}};
    int pl = wv * 16 + n16;
    int ho = y + (pl >> 5), wo = x0 + (pl & 31);
    float fybase = (float)(ho - 1), fxbase = (float)(wo - 1);

    int ky = 0, kx = 0;
    for (int k = 0; k < KTAPS; ++k) {
        // ---- bilinear params for (tap k, px pl), register-only ----
        float fy = omr[k * 64 + pl] + fybase + (float)ky;
        float fx = omr[(9 + k) * 64 + pl] + fxbase + (float)kx;
        float m = 1.f / (1.f + __expf(-omr[(18 + k) * 64 + pl]));
        float y0f = floorf(fy), x0f = floorf(fx);
        float dy = fy - y0f, dx = fx - x0f;
        int y0 = (int)y0f, x0i = (int)x0f;
        int y1 = y0 + 1, x1 = x0i + 1;
        bool vy0 = (y0 >= 0) & (y0 < HH);
        bool vy1 = (y1 >= 0) & (y1 < HH);
        bool vx0 = (x0i >= 0) & (x0i < WW);
        bool vx1 = (x1 >= 0) & (x1 < WW);
        float w00 = (1.f - dy) * (1.f - dx) * m; if (!(vy0 && vx0)) w00 = 0.f;
        float w01 = (1.f - dy) * dx * m;         if (!(vy0 && vx1)) w01 = 0.f;
        float w10 = dy * (1.f - dx) * m;         if (!(vy1 && vx0)) w10 = 0.f;
        float w11 = dy * dx * m;                 if (!(vy1 && vx1)) w11 = 0.f;
        int yc0 = min(max(y0, 0), HH - 1), yc1 = min(max(y1, 0), HH - 1);
        int xc0 = min(max(x0i, 0), WW - 1), xc1 = min(max(x1, 0), WW - 1);
        int uy = y0 - (y - 2), ux = x0i - (x0 - 2);
        bool inw = ((unsigned)uy <= 4u) & ((unsigned)ux <= 34u);
        unsigned int iu;
        if (inw) iu = (unsigned)(uy * TCOLS + ux);
        else     iu = 0x80000000u | ((unsigned)yc0 << 21) | ((unsigned)xc0 << 14)
                                  | ((unsigned)yc1 << 7)  | (unsigned)xc1;
        // advance (ky,kx) without div/mod
        if (++kx == 3) { kx = 0; ++ky; }

        // ---- per-half: A-frags + B-frag build + MFMA ----
#pragma unroll
        for (int h = 0; h < 2; ++h) {
            short8 af[4];
#pragma unroll
            for (int mt = 0; mt < 4; ++mt)
                af[mt] = *(const short8*)(wpk + (size_t)((mt * 18 + k * 2 + h) * 64 + lane) * 8);

            int g = h * 4 + quad;                 // channel-group / win segment
            uint4 qa, qb, qc, qd;
            if (__builtin_expect(!(iu & 0x80000000u), 1)) {
                const unsigned short* base = win + g * WSEGU + iu * 8;
                qa = *(const uint4*)(base);
                qb = *(const uint4*)(base + 8);
                qc = *(const uint4*)(base + TCOLS * 8);
                qd = *(const uint4*)(base + TCOLS * 8 + 8);
            } else {
                int zy0 = (iu >> 21) & 0x7f, zx0 = (iu >> 14) & 0x7f;
                int zy1 = (iu >> 7) & 0x7f,  zx1 = iu & 0x7f;
                const float* pc0 = xbf + (size_t)(g * 8) * HWSZ;
                auto ld8 = [&](int yy, int xx) {
                    const float* p = pc0 + yy * WW + xx;
                    unsigned int u0 = f2bf(p[0]),        u1 = f2bf(p[HWSZ]);
                    unsigned int u2 = f2bf(p[2 * HWSZ]), u3 = f2bf(p[3 * HWSZ]);
                    unsigned int u4 = f2bf(p[4 * HWSZ]), u5 = f2bf(p[5 * HWSZ]);
                    unsigned int u6 = f2bf(p[6 * HWSZ]), u7 = f2bf(p[7 * HWSZ]);
                    uint4 q;
                    q.x = u0 | (u1 << 16); q.y = u2 | (u3 << 16);
                    q.z = u4 | (u5 << 16); q.w = u6 | (u7 << 16);
                    return q;
                };
                qa = ld8(zy0, zx0); qb = ld8(zy0, zx1);
                qc = ld8(zy1, zx0); qd = ld8(zy1, zx1);
            }
            union { uint4 u; short8 s; } cv;
            cv.u.x = bilin2(qa.x, qb.x, qc.x, qd.x, w00, w01, w10, w11);
            cv.u.y = bilin2(qa.y, qb.y, qc.y, qd.y, w00, w01, w10, w11);
            cv.u.z = bilin2(qa.z, qb.z, qc.z, qd.z, w00, w01, w10, w11);
            cv.u.w = bilin2(qa.w, qb.w, qc.w, qd.w, w00, w01, w10, w11);
            short8 bfrag = cv.s;
#pragma unroll
            for (int mt = 0; mt < 4; ++mt) {
                acc[mt] = __builtin_amdgcn_mfma_f32_16x16x32_bf16(af[mt], bfrag,
                                                                  acc[mt], 0, 0, 0);
            }
        }
    }

    // Epilogue: D[m=quad*4+r][n=n16]; co = mt*16 + m; px = wv*16 + n16
    float* ob = out + (size_t)b * COUT * HWSZ;
    int gidx = (y + (pl >> 5)) * WW + x0 + (pl & 31);
#pragma unroll
    for (int mt = 0; mt < 4; ++mt) {
#pragma unroll
        for (int r = 0; r < 4; ++r) {
            int co = mt * 16 + quad * 4 + r;
            ob[(size_t)co * HWSZ + gidx] = acc[mt][r] + b_dcn[co];
        }
    }
}

// ---------------------------------------------------------------------------
extern "C" void kernel_launch(void* const* d_in, const int* in_sizes, int n_in,
                              void* d_out, int out_size, void* d_ws, size_t ws_size,
                              hipStream_t stream) {
    const float* x     = (const float*)d_in[0];
    const float* w_off = (const float*)d_in[1];
    const float* b_off = (const float*)d_in[2];
    const float* w_dcn = (const float*)d_in[3];
    const float* b_dcn = (const float*)d_in[4];
    float* out = (float*)d_out;

    // ws layout: wpk | wopk (bf16 repacked weights only)
    unsigned short* wpk  = (unsigned short*)d_ws;            // 36864
    unsigned short* wopk = wpk + 36864;                      // 18432

    hipLaunchKernelGGL(prep_w_kernel, dim3(216), dim3(256), 0, stream,
                       w_dcn, w_off, wpk, wopk);
    hipLaunchKernelGGL(dcn_fused_mfma, dim3(BATCH * HWSZ / 64), dim3(256),
                       0, stream, x, wpk, wopk, b_off, b_dcn, out);
}

// Round 5
// 129.248 us; speedup vs baseline: 1.1373x; 1.0086x over previous
//
#include <hip/hip_runtime.h>
#include <math.h>

#define BATCH 8
#define CH    64
#define HH    128
#define WW    128
#define HWSZ  (HH * WW)       // 16384
#define COUT  64
#define KTAPS 9
#define KDIM  576             // CH * KTAPS
#define TROWS 6               // window rows: y-2 .. y+3
#define TCOLS 36              // window cols: x0-2 .. x0+33
#define TSLOTS 216            // 6 * 36
#define WSEGU 1736            // ushorts per ch-segment (216*8=1728, +8 pad:
                              // 868 dw ≡ 4 mod 32 -> 8 segs on 8 bank phases)

typedef __attribute__((ext_vector_type(8))) short short8;
typedef __attribute__((ext_vector_type(4))) float f32x4;
typedef __attribute__((ext_vector_type(2))) float f32x2;

__device__ __forceinline__ unsigned short f2bf(float f) {
    unsigned int u = __float_as_uint(f);
    u += 0x7fffu + ((u >> 16) & 1u);
    return (unsigned short)(u >> 16);
}
// One-instruction packed fp32->bf16 (RNE), lo in [15:0], hi in [31:16].
// Compiler cannot form this from the bit-trick pattern; -3 VALU per use.
__device__ __forceinline__ unsigned int cvt_pk_bf16(float lo, float hi) {
    unsigned int r;
    asm("v_cvt_pk_bf16_f32 %0, %1, %2" : "=v"(r) : "v"(lo), "v"(hi));
    return r;
}
__device__ __forceinline__ f32x2 up2(unsigned int u) {
    f32x2 r;
    r.x = __uint_as_float(u << 16);
    r.y = __uint_as_float(u & 0xffff0000u);
    return r;
}
__device__ __forceinline__ unsigned int bilin2(unsigned int a, unsigned int b,
                                               unsigned int c, unsigned int d,
                                               float w00, float w01, float w10, float w11) {
    f32x2 acc = up2(a) * w00;
    acc = up2(b) * w01 + acc;
    acc = up2(c) * w10 + acc;
    acc = up2(d) * w11 + acc;
    return cvt_pk_bf16(acc.x, acc.y);
}

// ---------------------------------------------------------------------------
// Kernel 0: repack conv weights into wave-contiguous A-fragment layouts.
//  wpk [mt<4][ks<18][lane<64][8]: lane(n16,quad) holds
//      w_dcn[co=mt*16+n16][c=(ks&1)*32+quad*8+j], tap=ks>>1
//  wopk[cot<2][ks<18][lane<64][8]: same for w_off (co>=27 zeroed)
// ---------------------------------------------------------------------------
__global__ __launch_bounds__(256) void prep_w_kernel(
    const float* __restrict__ w_dcn, const float* __restrict__ w_off,
    unsigned short* __restrict__ wpk, unsigned short* __restrict__ wopk) {
    int j = blockIdx.x * 256 + threadIdx.x;
    if (j < 36864) {
        int jj = j & 7, ln = (j >> 3) & 63, q = j >> 9;   // q: 0..71
        int ks = q % 18, mt = q / 18;
        int tap = ks >> 1, h = ks & 1;
        int co = mt * 16 + (ln & 15);
        int c  = h * 32 + (ln >> 4) * 8 + jj;
        wpk[j] = f2bf(w_dcn[(co * CH + c) * KTAPS + tap]);
    } else if (j < 55296) {
        int jo = j - 36864;
        int jj = jo & 7, ln = (jo >> 3) & 63, q = jo >> 9; // q: 0..35
        int ks = q % 18, cot = q / 18;
        int tap = ks >> 1, h = ks & 1;
        int co = cot * 16 + (ln & 15);
        int c  = h * 32 + (ln >> 4) * 8 + jj;
        wopk[jo] = (co < 27) ? f2bf(w_off[(co * CH + c) * KTAPS + tap]) : 0;
    }
}

// ---------------------------------------------------------------------------
// Kernel 1: SINGLE FUSED DCN. Block tile = 2 rows x 32 cols (64 px).
//  Stage: win[c8][216 slots][8ch] bf16 <- 6x36 neighborhood straight from
//         NCHW fp32 x (zero-padded OOB). Bank-clean (WSEGU pad). Packing via
//         v_cvt_pk_bf16_f32 (4 inst/slot instead of ~38).
//  Phase 1: offset GEMM 32co x 64px, B-frags ds_read_b128 from window.
//  Phase 3 (params fused per tap): per-tap scalars only (R3 lesson: arrays
//           spill). unroll 3 so tap k+1's omr/corner ds_reads hide under
//           tap k's bilin+MFMA.
// LDS: win 27776 | omr 6912 = 34688 B -> 4 blocks/CU (16 waves).
// Reg budget: launch_bounds(256,4) caps at 128 VGPR.
// ---------------------------------------------------------------------------
__global__ __launch_bounds__(256, 4) void dcn_fused_mfma(
    const float* __restrict__ x, const unsigned short* __restrict__ wpk,
    const unsigned short* __restrict__ wopk, const float* __restrict__ b_off,
    const float* __restrict__ b_dcn, float* __restrict__ out) {
    __shared__ __align__(16) unsigned char smem[34688];
    unsigned short* win = (unsigned short*)smem;           // [8][WSEGU]
    float* omr = (float*)(smem + 27776);                   // [27][64]

    int tid = threadIdx.x, bid = blockIdx.x;
    int b = bid & 7;                 // batch -> XCD pinning
    int T = bid >> 3;                // tile 0..255 per image
    int y = (T >> 2) * 2;            // tile row base (2 rows)
    int x0 = (T & 3) * 32;           // tile col base
    int lane = tid & 63, wv = tid >> 6;
    int quad = lane >> 4, n16 = lane & 15;

    const float* xbf = x + (size_t)b * CH * HWSZ;

    // ---------------- Stage window from NCHW fp32 ----------------
    for (int p = tid; p < 8 * TSLOTS; p += 256) {
        int c8 = p / TSLOTS, slot = p - c8 * TSLOTS;
        int wy = slot / TCOLS, wx = slot - wy * TCOLS;
        int iy = y - 2 + wy, ix = x0 - 2 + wx;
        bool v = (iy >= 0) & (iy < HH) & (ix >= 0) & (ix < WW);
        uint4 q = {0, 0, 0, 0};
        if (v) {
            const float* pc0 = xbf + (size_t)(c8 * 8) * HWSZ + iy * WW + ix;
            float f0 = pc0[0],        f1 = pc0[HWSZ];
            float f2 = pc0[2 * HWSZ], f3 = pc0[3 * HWSZ];
            float f4 = pc0[4 * HWSZ], f5 = pc0[5 * HWSZ];
            float f6 = pc0[6 * HWSZ], f7 = pc0[7 * HWSZ];
            q.x = cvt_pk_bf16(f0, f1);
            q.y = cvt_pk_bf16(f2, f3);
            q.z = cvt_pk_bf16(f4, f5);
            q.w = cvt_pk_bf16(f6, f7);
        }
        *(uint4*)&win[c8 * WSEGU + slot * 8] = q;
    }
    __syncthreads();

    // ---------------- Phase 1: offset GEMM (B from window) ----------------
    {
        int coh = wv & 1;
        int pxh = (wv >> 1) * 32;
        int prw = wv >> 1;               // this wave's px row within tile
        f32x4 oacc[2] = {{0, 0, 0, 0}, {0, 0, 0, 0}};
        for (int k = 0; k < KTAPS; ++k) {
            int ky = k / 3, kx = k - ky * 3;
#pragma unroll
            for (int h = 0; h < 2; ++h) {
                short8 afrag = *(const short8*)(wopk + (size_t)((coh * 18 + k * 2 + h) * 64 + lane) * 8);
                const unsigned short* seg = win + (h * 4 + quad) * WSEGU;
#pragma unroll
                for (int pt = 0; pt < 2; ++pt) {
                    int pc = pt * 16 + n16;
                    int slot = (prw + ky + 1) * TCOLS + pc + kx + 1;
                    short8 bfrag = *(const short8*)(seg + slot * 8);
                    oacc[pt] = __builtin_amdgcn_mfma_f32_16x16x32_bf16(afrag, bfrag,
                                                                       oacc[pt], 0, 0, 0);
                }
            }
        }
#pragma unroll
        for (int pt = 0; pt < 2; ++pt) {
#pragma unroll
            for (int r = 0; r < 4; ++r) {
                int co = coh * 16 + quad * 4 + r;
                if (co < 27) omr[co * 64 + pxh + pt * 16 + n16] = oacc[pt][r] + b_off[co];
            }
        }
    }
    __syncthreads();

    // ---------------- Phase 3: main GEMM, params fused per tap ------------
    // Wave wv owns px = wv*16 + n16 (all 64 co). Lane (quad,n16) builds the
    // exact MFMA B-fragment: channels h*32+quad*8+j of its px, h = 0,1.
    // Per tap: 3 omr reads (quad-broadcast) -> scalars -> window/global
    // corners -> bilin -> 8 MFMA. No persistent arrays beyond acc.
    f32x4 acc[4] = {{0, 0, 0, 0}, {0, 0, 0, 0}, {0, 0, 0, 0}, {0, 0, 0, 0}};
    int pl = wv * 16 + n16;
    int ho = y + (pl >> 5), wo = x0 + (pl & 31);
    float fybase = (float)(ho - 1), fxbase = (float)(wo - 1);

#pragma unroll 3
    for (int k = 0; k < KTAPS; ++k) {
        int ky = k / 3, kx = k - ky * 3;   // k const per unrolled copy
        // ---- bilinear params for (tap k, px pl), register-only ----
        float fy = omr[k * 64 + pl] + fybase + (float)ky;
        float fx = omr[(9 + k) * 64 + pl] + fxbase + (float)kx;
        float m = 1.f / (1.f + __expf(-omr[(18 + k) * 64 + pl]));
        float y0f = floorf(fy), x0f = floorf(fx);
        float dy = fy - y0f, dx = fx - x0f;
        int y0 = (int)y0f, x0i = (int)x0f;
        int y1 = y0 + 1, x1 = x0i + 1;
        bool vy0 = (y0 >= 0) & (y0 < HH);
        bool vy1 = (y1 >= 0) & (y1 < HH);
        bool vx0 = (x0i >= 0) & (x0i < WW);
        bool vx1 = (x1 >= 0) & (x1 < WW);
        float w00 = (1.f - dy) * (1.f - dx) * m; if (!(vy0 && vx0)) w00 = 0.f;
        float w01 = (1.f - dy) * dx * m;         if (!(vy0 && vx1)) w01 = 0.f;
        float w10 = dy * (1.f - dx) * m;         if (!(vy1 && vx0)) w10 = 0.f;
        float w11 = dy * dx * m;                 if (!(vy1 && vx1)) w11 = 0.f;
        int yc0 = min(max(y0, 0), HH - 1), yc1 = min(max(y1, 0), HH - 1);
        int xc0 = min(max(x0i, 0), WW - 1), xc1 = min(max(x1, 0), WW - 1);
        int uy = y0 - (y - 2), ux = x0i - (x0 - 2);
        bool inw = ((unsigned)uy <= 4u) & ((unsigned)ux <= 34u);
        unsigned int iu;
        if (inw) iu = (unsigned)(uy * TCOLS + ux);
        else     iu = 0x80000000u | ((unsigned)yc0 << 21) | ((unsigned)xc0 << 14)
                                  | ((unsigned)yc1 << 7)  | (unsigned)xc1;

        // ---- per-half: A-frags + B-frag build + MFMA ----
#pragma unroll
        for (int h = 0; h < 2; ++h) {
            short8 af[4];
#pragma unroll
            for (int mt = 0; mt < 4; ++mt)
                af[mt] = *(const short8*)(wpk + (size_t)((mt * 18 + k * 2 + h) * 64 + lane) * 8);

            int g = h * 4 + quad;                 // channel-group / win segment
            uint4 qa, qb, qc, qd;
            if (__builtin_expect(!(iu & 0x80000000u), 1)) {
                const unsigned short* base = win + g * WSEGU + iu * 8;
                qa = *(const uint4*)(base);
                qb = *(const uint4*)(base + 8);
                qc = *(const uint4*)(base + TCOLS * 8);
                qd = *(const uint4*)(base + TCOLS * 8 + 8);
            } else {
                int zy0 = (iu >> 21) & 0x7f, zx0 = (iu >> 14) & 0x7f;
                int zy1 = (iu >> 7) & 0x7f,  zx1 = iu & 0x7f;
                const float* pc0 = xbf + (size_t)(g * 8) * HWSZ;
                auto ld8 = [&](int yy, int xx) {
                    const float* p = pc0 + yy * WW + xx;
                    uint4 q;
                    q.x = cvt_pk_bf16(p[0],        p[HWSZ]);
                    q.y = cvt_pk_bf16(p[2 * HWSZ], p[3 * HWSZ]);
                    q.z = cvt_pk_bf16(p[4 * HWSZ], p[5 * HWSZ]);
                    q.w = cvt_pk_bf16(p[6 * HWSZ], p[7 * HWSZ]);
                    return q;
                };
                qa = ld8(zy0, zx0); qb = ld8(zy0, zx1);
                qc = ld8(zy1, zx0); qd = ld8(zy1, zx1);
            }
            union { uint4 u; short8 s; } cv;
            cv.u.x = bilin2(qa.x, qb.x, qc.x, qd.x, w00, w01, w10, w11);
            cv.u.y = bilin2(qa.y, qb.y, qc.y, qd.y, w00, w01, w10, w11);
            cv.u.z = bilin2(qa.z, qb.z, qc.z, qd.z, w00, w01, w10, w11);
            cv.u.w = bilin2(qa.w, qb.w, qc.w, qd.w, w00, w01, w10, w11);
            short8 bfrag = cv.s;
#pragma unroll
            for (int mt = 0; mt < 4; ++mt) {
                acc[mt] = __builtin_amdgcn_mfma_f32_16x16x32_bf16(af[mt], bfrag,
                                                                  acc[mt], 0, 0, 0);
            }
        }
    }

    // Epilogue: D[m=quad*4+r][n=n16]; co = mt*16 + m; px = wv*16 + n16
    float* ob = out + (size_t)b * COUT * HWSZ;
    int gidx = (y + (pl >> 5)) * WW + x0 + (pl & 31);
#pragma unroll
    for (int mt = 0; mt < 4; ++mt) {
#pragma unroll
        for (int r = 0; r < 4; ++r) {
            int co = mt * 16 + quad * 4 + r;
            ob[(size_t)co * HWSZ + gidx] = acc[mt][r] + b_dcn[co];
        }
    }
}

// ---------------------------------------------------------------------------
extern "C" void kernel_launch(void* const* d_in, const int* in_sizes, int n_in,
                              void* d_out, int out_size, void* d_ws, size_t ws_size,
                              hipStream_t stream) {
    const float* x     = (const float*)d_in[0];
    const float* w_off = (const float*)d_in[1];
    const float* b_off = (const float*)d_in[2];
    const float* w_dcn = (const float*)d_in[3];
    const float* b_dcn = (const float*)d_in[4];
    float* out = (float*)d_out;

    // ws layout: wpk | wopk (bf16 repacked weights only)
    unsigned short* wpk  = (unsigned short*)d_ws;            // 36864
    unsigned short* wopk = wpk + 36864;                      // 18432

    hipLaunchKernelGGL(prep_w_kernel, dim3(216), dim3(256), 0, stream,
                       w_dcn, w_off, wpk, wopk);
    hipLaunchKernelGGL(dcn_fused_mfma, dim3(BATCH * HWSZ / 64), dim3(256),
                       0, stream, x, wpk, wopk, b_off, b_dcn, out);
}